// Round 10
// baseline (1678.078 us; speedup 1.0000x reference)
//
#include <hip/hip_runtime.h>
#include <hip/hip_bf16.h>
#include <math.h>

typedef __attribute__((ext_vector_type(8))) __bf16 bf16x8;
typedef __attribute__((ext_vector_type(8))) short short8;
typedef __attribute__((ext_vector_type(4))) float f32x4;
typedef __attribute__((ext_vector_type(4))) unsigned short ushort4v;

#define AS1 __attribute__((address_space(1)))
#define AS3 __attribute__((address_space(3)))

__device__ __forceinline__ unsigned short f2bf(float f) {
  __hip_bfloat16 h = __float2bfloat16(f);
  return __builtin_bit_cast(unsigned short, h);
}
__device__ __forceinline__ float bf2f(unsigned short s) {
  unsigned int u = ((unsigned int)s) << 16;
  return __builtin_bit_cast(float, u);
}

// fast exact-shape gelu: 0.5*v*(1+erf(v/sqrt2)), erf via A&S 7.1.26 (|err|<1.5e-7)
__device__ __forceinline__ float fast_gelu(float v) {
  const float x = v * 0.70710678118654752f;
  const float a = __builtin_fabsf(x);
  const float t = __builtin_amdgcn_rcpf(__builtin_fmaf(0.3275911f, a, 1.0f));
  float p = __builtin_fmaf(t, 1.061405429f, -1.453152027f);
  p = __builtin_fmaf(t, p, 1.421413741f);
  p = __builtin_fmaf(t, p, -0.284496736f);
  p = __builtin_fmaf(t, p, 0.254829592f);
  p = p * t;
  const float e = __builtin_amdgcn_exp2f(-a * a * 1.4426950408889634f);
  const float erfa = __builtin_fmaf(-p, e, 1.0f);
  const float erfx = __builtin_copysignf(erfa, x);
  return 0.5f * v * (1.0f + erfx);
}

// ---------- fp32 -> bf16 conversion ----------
__global__ void cvt_f32_bf16(const float4* __restrict__ in,
                             ushort4v* __restrict__ out, size_t n4) {
  size_t i = (size_t)blockIdx.x * blockDim.x + threadIdx.x;
  size_t stride = (size_t)gridDim.x * blockDim.x;
  for (; i < n4; i += stride) {
    float4 v = in[i];
    ushort4v o = { f2bf(v.x), f2bf(v.y), f2bf(v.z), f2bf(v.w) };
    out[i] = o;
  }
}

#define MFMA16(a, b, c) __builtin_amdgcn_mfma_f32_16x16x32_bf16( \
    __builtin_bit_cast(bf16x8, a), __builtin_bit_cast(bf16x8, b), c, 0, 0, 0)

// ---------- 256x256 bf16 GEMM: C = A[M,K](lda) * B[N,K]^T (+bias) ----------
// r10: BK=32 full-tile ring-5 (5 x 32KB = 160 KB LDS). Stage the WHOLE tile
// t+2 during tile t (4 gload_lds/thread, static kinds, scalar base pointers
// advanced +=32/tile) -> the tile consumed at boundary t was staged 2 full
// tiles (~5000 cyc) earlier: vmcnt(4) never waits on HBM latency.
// Slot safety: slot (t+2)%5 written during tile t was last read as tile t-3,
// separated by 3 boundary barriers (+ per-wave lgkm drains before MFMA use).
// Tile-slot layout: [A0 0..4095][A1 4096..8191][B0 8192..12287][B1 12288..16383]
// elems; each 8KB unit = 128 rows x 32 k packed as [64 lds-rows][8 slots of 8],
// phys slot = slog^(lrow&7), row = lrow*2+(slog>>2), chunk = slog&3
// (r4-verified: correct + zero bank conflicts). Staging writes are linear
// (thread p -> bytes p*16 of the unit); source address pre-inverse-swizzled.
// Per tile: 12 ds_read_b128 -> stage(t+2) -> lgkm(compiler) -> 32 MFMA
// (setprio) ; boundary = vmcnt(4)+barrier, one per tile.
// 8 waves (2M x 4N), per-wave 128x64 out, 16x16x32 MFMA (one k-step per tile).
// EPI 0: Cb = bf16(gelu(v))          (v = acc + bias[col])
// EPI 1: Cf  = wgt[row*8+eidx] * v
// EPI 2: Cf += wgt[row*8+eidx] * v
// EPI 3: Cf[z*cZ + ...] = wgt[row*8+z] * v   (grouped partials)
template<int EPI>
__global__ __launch_bounds__(512, 2)
void gemm256(const unsigned short* __restrict__ A, size_t aZ, int lda,
             const unsigned short* __restrict__ B, size_t bZ,
             const float* __restrict__ bias, size_t biasZ,
             unsigned short* __restrict__ Cb, float* __restrict__ Cf, size_t cZ,
             const float* __restrict__ wgt, int eidx,
             int M, int N, int K) {
  __shared__ alignas(16) unsigned short sm[81920];  // 5 slots x 16384 elems
  const int tid  = threadIdx.x;
  const int lane = tid & 63;
  const int wid  = tid >> 6;
  const int wr   = wid >> 2;   // 0..1  -> A unit
  const int wc   = wid & 3;    // 0..3  -> B unit = wc>>1, 64-row sub = wc&1
  const int z    = blockIdx.z;

  // XCD-aware swizzle (all grids here have gx*gy % 8 == 0)
  const int gx  = gridDim.x;
  const int nwg = gx * gridDim.y;
  const int lin = blockIdx.y * gx + blockIdx.x;
  const int cpx = nwg >> 3;
  const int swb = (lin & 7) * cpx + (lin >> 3);
  const int bm = (swb / gx) * 256;
  const int bn = (swb % gx) * 256;

  // scalar base pointers (advanced += 32 per staged tile)
  const unsigned short* pA0 = A + z * aZ + (size_t)bm * lda;
  const unsigned short* pA1 = pA0 + (size_t)128 * lda;
  const unsigned short* pB0 = B + z * bZ + (size_t)bn * K;
  const unsigned short* pB1 = pB0 + (size_t)128 * K;

  // per-lane static staging offsets: thread p -> unit bytes [p*16, p*16+16)
  // lrow=p>>3, sphys=p&7, slog=sphys^(lrow&7), row=lrow*2+(slog>>2), chunk=slog&3
  const int p0    = tid;
  const int lrow0 = p0 >> 3;
  const int slog0 = (p0 & 7) ^ (lrow0 & 7);
  const int srow  = lrow0 * 2 + (slog0 >> 2);
  const int schk  = (slog0 & 3) * 8;
  const unsigned a_off = (unsigned)(srow * lda + schk);
  const unsigned b_off = (unsigned)(srow * K + schk);
  const int ldo = tid * 8;   // elems within unit

  const int NT = K >> 5;     // BK = 32

  auto stage_tile = [&](int slot) {
    unsigned short* d = &sm[slot * 16384];
    __builtin_amdgcn_global_load_lds((const AS1 void*)(pA0 + a_off),
        (AS3 void*)(d + ldo), 16, 0, 0);
    __builtin_amdgcn_global_load_lds((const AS1 void*)(pA1 + a_off),
        (AS3 void*)(d + 4096 + ldo), 16, 0, 0);
    __builtin_amdgcn_global_load_lds((const AS1 void*)(pB0 + b_off),
        (AS3 void*)(d + 8192 + ldo), 16, 0, 0);
    __builtin_amdgcn_global_load_lds((const AS1 void*)(pB1 + b_off),
        (AS3 void*)(d + 12288 + ldo), 16, 0, 0);
    pA0 += 32; pA1 += 32; pB0 += 32; pB1 += 32;
  };

  f32x4 acc[8][4] = {};
  // frag read offsets (elems within tile-slot):
  // row = base + laneq, k-chunk g = lane>>4; lrow&7 == laneq>>1 for all frags
  const int g   = lane >> 4;
  const int lq  = lane & 15;
  const int lr  = lq >> 1;
  const int sph = (((lq & 1) << 2) + g) ^ lr;
  const int swA = wr * 4096 + lr * 64 + sph * 8;                    // + mf*512
  const int swB = 8192 + (wc >> 1) * 4096 + (wc & 1) * 2048 + lr * 64 + sph * 8;

  // prologue: stage tiles 0 and 1
  stage_tile(0);
  if (NT > 1) stage_tile(1);

  int sr = 0, sw2 = 2;   // read slot (t%5), write slot ((t+2)%5)
  for (int t = 0; t < NT; ++t) {
    if (t + 1 < NT) asm volatile("s_waitcnt vmcnt(4)" ::: "memory");
    else            asm volatile("s_waitcnt vmcnt(0)" ::: "memory");
    __builtin_amdgcn_s_barrier();
    asm volatile("" ::: "memory");

    const unsigned short* pa = &sm[sr * 16384 + swA];
    const unsigned short* pb = &sm[sr * 16384 + swB];
    short8 af[8], bf[4];
#pragma unroll
    for (int mf = 0; mf < 8; ++mf) af[mf] = *(const short8*)(pa + mf * 512);
#pragma unroll
    for (int nf = 0; nf < 4; ++nf) bf[nf] = *(const short8*)(pb + nf * 512);

    if (t + 2 < NT) stage_tile(sw2);

    __builtin_amdgcn_s_setprio(1);
#pragma unroll
    for (int mf = 0; mf < 8; ++mf)
#pragma unroll
      for (int nf = 0; nf < 4; ++nf)
        acc[mf][nf] = MFMA16(af[mf], bf[nf], acc[mf][nf]);
    __builtin_amdgcn_s_setprio(0);

    sr  = (sr  == 4) ? 0 : sr + 1;
    sw2 = (sw2 == 4) ? 0 : sw2 + 1;
  }

  // epilogue: C/D layout col=lane&15, row=(lane>>4)*4+reg
  const int rbase = bm + wr * 128 + ((lane >> 4) << 2);
  const int cbase = bn + wc * 64 + (lane & 15);
  float wv[8][4];
  if (EPI != 0) {
    const int ei = (EPI == 3) ? z : eidx;
#pragma unroll
    for (int mf = 0; mf < 8; ++mf)
#pragma unroll
      for (int r = 0; r < 4; ++r)
        wv[mf][r] = wgt[(size_t)(rbase + mf * 16 + r) * 8 + ei];
  }
#pragma unroll
  for (int mf = 0; mf < 8; ++mf) {
#pragma unroll
    for (int nf = 0; nf < 4; ++nf) {
      const int col = cbase + nf * 16;
      const float bv = bias[z * biasZ + col];
#pragma unroll
      for (int r = 0; r < 4; ++r) {
        const int row = rbase + mf * 16 + r;
        const float v = acc[mf][nf][r] + bv;
        if (EPI == 0) {
          Cb[z * cZ + (size_t)row * N + col] = f2bf(fast_gelu(v));
        } else if (EPI == 1) {
          Cf[(size_t)row * N + col] = wv[mf][r] * v;
        } else if (EPI == 2) {
          Cf[(size_t)row * N + col] += wv[mf][r] * v;
        } else {
          Cf[z * cZ + (size_t)row * N + col] = wv[mf][r] * v;
        }
      }
    }
  }
}

// ---------- gate logits (E=8) + softmax, 1 block/token ----------
__global__ void gate_softmax(const unsigned short* __restrict__ g2,
                             const unsigned short* __restrict__ W3,
                             const float* __restrict__ b3,
                             float* __restrict__ wout, int H) {
  const int m = blockIdx.x;
  const int lane = threadIdx.x & 63;
  const int wid  = threadIdx.x >> 6;
  float acc[8] = {0.f, 0.f, 0.f, 0.f, 0.f, 0.f, 0.f, 0.f};
  const unsigned short* grow = g2 + (size_t)m * H;
  for (int k = threadIdx.x * 8; k < H; k += 256 * 8) {
    short8 gv = *(const short8*)(grow + k);
    float gf[8];
#pragma unroll
    for (int j = 0; j < 8; ++j) gf[j] = bf2f((unsigned short)gv[j]);
#pragma unroll
    for (int e = 0; e < 8; ++e) {
      short8 wvv = *(const short8*)(W3 + (size_t)e * H + k);
#pragma unroll
      for (int j = 0; j < 8; ++j) acc[e] += gf[j] * bf2f((unsigned short)wvv[j]);
    }
  }
#pragma unroll
  for (int e = 0; e < 8; ++e)
#pragma unroll
    for (int off = 32; off > 0; off >>= 1) acc[e] += __shfl_down(acc[e], off);
  __shared__ float red[4][8];
  if (lane == 0) {
#pragma unroll
    for (int e = 0; e < 8; ++e) red[wid][e] = acc[e];
  }
  __syncthreads();
  if (threadIdx.x == 0) {
    float l[8], mx = -1e30f, s = 0.f;
#pragma unroll
    for (int e = 0; e < 8; ++e) {
      l[e] = red[0][e] + red[1][e] + red[2][e] + red[3][e] + b3[e];
      mx = fmaxf(mx, l[e]);
    }
#pragma unroll
    for (int e = 0; e < 8; ++e) { l[e] = expf(l[e] - mx); s += l[e]; }
    const float inv = 1.f / s;
#pragma unroll
    for (int e = 0; e < 8; ++e) wout[(size_t)m * 8 + e] = l[e] * inv;
  }
}

// ---------- sum of 8 expert partials ----------
__global__ void reduce8(const float4* __restrict__ in, float4* __restrict__ out,
                        int n4) {
  int i = blockIdx.x * 256 + threadIdx.x;
  const int stride = gridDim.x * 256;
  for (; i < n4; i += stride) {
    float4 s = in[i];
#pragma unroll
    for (int zz = 1; zz < 8; ++zz) {
      float4 v = in[(size_t)zz * n4 + i];
      s.x += v.x; s.y += v.y; s.z += v.z; s.w += v.w;
    }
    out[i] = s;
  }
}

extern "C" void kernel_launch(void* const* d_in, const int* in_sizes, int n_in,
                              void* d_out, int out_size, void* d_ws, size_t ws_size,
                              hipStream_t stream) {
  const float* x   = (const float*)d_in[0];
  const float* gW1 = (const float*)d_in[1];
  const float* gb1 = (const float*)d_in[2];
  const float* gW2 = (const float*)d_in[3];
  const float* gb2 = (const float*)d_in[4];
  const float* gW3 = (const float*)d_in[5];
  const float* gb3 = (const float*)d_in[6];
  const float* eW1 = (const float*)d_in[7];
  const float* eb1 = (const float*)d_in[8];
  const float* eW2 = (const float*)d_in[9];
  const float* eb2 = (const float*)d_in[10];

  const int M = 4096, D = 1024, H = 4096, E = 8;
  const int NCAT = (1 + E) * H;   // 36864: [gate1 | expert1 x8] fused columns

  float* outP = (float*)d_out;              // [M, D]
  float* wP   = outP + (size_t)M * D;       // [M, E]

  char* ws = (char*)d_ws;
  size_t off = 0;
  auto alloc = [&](size_t bytes) -> void* {
    void* p = ws + off;
    off += (bytes + 255) & ~(size_t)255;
    return p;
  };
  unsigned short* xb    = (unsigned short*)alloc((size_t)M * D * 2);
  unsigned short* w1cat = (unsigned short*)alloc((size_t)NCAT * D * 2);
  unsigned short* gW2b  = (unsigned short*)alloc((size_t)H * H * 2);
  unsigned short* gW3b  = (unsigned short*)alloc((size_t)E * H * 2);
  unsigned short* eW2b  = (unsigned short*)alloc((size_t)E * D * H * 2);
  unsigned short* g2b   = (unsigned short*)alloc((size_t)M * H * 2);
  float*          b1cat = (float*)alloc((size_t)NCAT * 4);
  unsigned short* h_cat = (unsigned short*)alloc((size_t)M * NCAT * 2);
  const size_t base_off = off;
  const size_t eo_b = (size_t)E * M * D * 4;   // 128 MB
  const int tier1 = (ws_size >= base_off + eo_b) ? 1 : 0;

  auto cvt = [&](const float* src, unsigned short* dst, size_t n) {
    size_t n4 = n >> 2;
    size_t b = (n4 + 255) >> 8;
    if (b > 2048) b = 2048;
    cvt_f32_bf16<<<dim3((unsigned)b), dim3(256), 0, stream>>>(
        (const float4*)src, (ushort4v*)dst, n4);
  };
  cvt(x,   xb,    (size_t)M * D);
  cvt(gW1, w1cat, (size_t)H * D);
  cvt(eW1, w1cat + (size_t)H * D, (size_t)E * H * D);
  cvt(gW2, gW2b,  (size_t)H * H);
  cvt(gW3, gW3b,  (size_t)E * H);
  cvt(eW2, eW2b,  (size_t)E * D * H);
  hipMemcpyAsync(b1cat, gb1, (size_t)H * 4, hipMemcpyDeviceToDevice, stream);
  hipMemcpyAsync(b1cat + H, eb1, (size_t)E * H * 4, hipMemcpyDeviceToDevice, stream);

  // fused layer-1: h_cat = gelu(x @ [gW1;eW1]^T + b1cat)   [M, 36864], K=D
  gemm256<0><<<dim3(NCAT / 256, M / 256, 1), dim3(512), 0, stream>>>(
      xb, 0, D, w1cat, 0, b1cat, 0, h_cat, nullptr, 0, nullptr, 0, M, NCAT, D);
  // gate2: g2 = gelu(g1 @ gW2^T + gb2)  [M,H], K=H  (A = h_cat cols [0,H))
  gemm256<0><<<dim3(H / 256, M / 256, 1), dim3(512), 0, stream>>>(
      h_cat, 0, NCAT, gW2b, 0, gb2, 0, g2b, nullptr, 0, nullptr, 0, M, H, H);
  // softmax weights
  gate_softmax<<<dim3(M), dim3(256), 0, stream>>>(g2b, gW3b, gb3, wP, H);

  if (tier1) {
    float* eo_all = (float*)alloc(eo_b);
    // expert layer 2 grouped -> weighted partials (A = h_cat cols [H+z*H, ...))
    gemm256<3><<<dim3(D / 256, M / 256, E), dim3(512), 0, stream>>>(
        h_cat + H, (size_t)H, NCAT, eW2b, (size_t)D * H, eb2, D,
        nullptr, eo_all, (size_t)M * D, wP, 0, M, D, H);
    reduce8<<<dim3(2048), dim3(256), 0, stream>>>(
        (const float4*)eo_all, (float4*)outP, (int)((size_t)M * D / 4));
  } else {
    for (int e = 0; e < E; ++e) {
      if (e == 0)
        gemm256<1><<<dim3(D / 256, M / 256, 1), dim3(512), 0, stream>>>(
            h_cat + (size_t)(1 + e) * H, 0, NCAT, eW2b + (size_t)e * D * H, 0,
            eb2 + (size_t)e * D, 0, nullptr, outP, 0, wP, e, M, D, H);
      else
        gemm256<2><<<dim3(D / 256, M / 256, 1), dim3(512), 0, stream>>>(
            h_cat + (size_t)(1 + e) * H, 0, NCAT, eW2b + (size_t)e * D * H, 0,
            eb2 + (size_t)e * D, 0, nullptr, outP, 0, wP, e, M, D, H);
    }
  }
}

// Round 11
// 1514.853 us; speedup vs baseline: 1.1077x; 1.1077x over previous
//
#include <hip/hip_runtime.h>
#include <hip/hip_bf16.h>
#include <math.h>

typedef __attribute__((ext_vector_type(8))) __bf16 bf16x8;
typedef __attribute__((ext_vector_type(8))) short short8;
typedef __attribute__((ext_vector_type(4))) float f32x4;
typedef __attribute__((ext_vector_type(4))) unsigned short ushort4v;

#define AS1 __attribute__((address_space(1)))
#define AS3 __attribute__((address_space(3)))

__device__ __forceinline__ unsigned short f2bf(float f) {
  __hip_bfloat16 h = __float2bfloat16(f);
  return __builtin_bit_cast(unsigned short, h);
}
__device__ __forceinline__ float bf2f(unsigned short s) {
  unsigned int u = ((unsigned int)s) << 16;
  return __builtin_bit_cast(float, u);
}

// fast exact-shape gelu: 0.5*v*(1+erf(v/sqrt2)), erf via A&S 7.1.26 (|err|<1.5e-7)
__device__ __forceinline__ float fast_gelu(float v) {
  const float x = v * 0.70710678118654752f;
  const float a = __builtin_fabsf(x);
  const float t = __builtin_amdgcn_rcpf(__builtin_fmaf(0.3275911f, a, 1.0f));
  float p = __builtin_fmaf(t, 1.061405429f, -1.453152027f);
  p = __builtin_fmaf(t, p, 1.421413741f);
  p = __builtin_fmaf(t, p, -0.284496736f);
  p = __builtin_fmaf(t, p, 0.254829592f);
  p = p * t;
  const float e = __builtin_amdgcn_exp2f(-a * a * 1.4426950408889634f);
  const float erfa = __builtin_fmaf(-p, e, 1.0f);
  const float erfx = __builtin_copysignf(erfa, x);
  return 0.5f * v * (1.0f + erfx);
}

// ---------- fp32 -> bf16 conversion ----------
__global__ void cvt_f32_bf16(const float4* __restrict__ in,
                             ushort4v* __restrict__ out, size_t n4) {
  size_t i = (size_t)blockIdx.x * blockDim.x + threadIdx.x;
  size_t stride = (size_t)gridDim.x * blockDim.x;
  for (; i < n4; i += stride) {
    float4 v = in[i];
    ushort4v o = { f2bf(v.x), f2bf(v.y), f2bf(v.z), f2bf(v.w) };
    out[i] = o;
  }
}

#define MFMA16(a, b, c) __builtin_amdgcn_mfma_f32_16x16x32_bf16( \
    __builtin_bit_cast(bf16x8, a), __builtin_bit_cast(bf16x8, b), c, 0, 0, 0)

// ---------- 256x256 bf16 GEMM: C = A[M,K](lda) * B[N,K]^T (+bias) ----------
// r9 core (best): 10-slot half-tile LDS ring (160 KB), lead 6 halves, ONE
// barrier per K-tile (boundary vmcnt(4)+s_barrier), wave anti-phasing, k-
// outermost MFMA nests.
// r11 change: EPI 0 writes into SEGMENTED output — segment s = col>>12 is a
// contiguous [M,4096] buffer at Cb + s*cZ (cZ = M*4096). This keeps h_cat's
// consumers (gate2 / expert2) reading DENSE lda=4096 A-panels instead of
// lda=36864 strided rows (256 DRAM pages per half-tile -> HBM latency killer).
// EPI 0: Cb[seg] = bf16(gelu(v))     (v = acc + bias[col])
// EPI 1: Cf  = wgt[row*8+eidx] * v
// EPI 2: Cf += wgt[row*8+eidx] * v
// EPI 3: Cf[z*cZ + ...] = wgt[row*8+z] * v   (grouped partials)
template<int EPI>
__global__ __launch_bounds__(512, 2)
void gemm256(const unsigned short* __restrict__ A, size_t aZ, int lda,
             const unsigned short* __restrict__ B, size_t bZ,
             const float* __restrict__ bias, size_t biasZ,
             unsigned short* __restrict__ Cb, float* __restrict__ Cf, size_t cZ,
             const float* __restrict__ wgt, int eidx,
             int M, int N, int K) {
  __shared__ alignas(16) unsigned short sm[81920];  // 10 slots x 8192 = 160 KB
  const int tid  = threadIdx.x;
  const int lane = tid & 63;
  const int wid  = tid >> 6;
  const int wr   = wid >> 2;   // 0..1  -> A-half AND SIMD-pair parity
  const int wc   = wid & 3;    // 0..3  -> B-half = wc>>1
  const int z    = blockIdx.z;

  // XCD-aware swizzle (all grids here have gx*gy % 8 == 0)
  const int gx  = gridDim.x;
  const int nwg = gx * gridDim.y;
  const int lin = blockIdx.y * gx + blockIdx.x;
  const int cpx = nwg >> 3;
  const int swb = (lin & 7) * cpx + (lin >> 3);
  const int bm = (swb / gx) * 256;
  const int bn = (swb % gx) * 256;

  const unsigned short* Ab = A + z * aZ + (size_t)bm * lda;  // uniform (SGPR)
  const unsigned short* Bb = B + z * bZ + (size_t)bn * K;

  // staging: 2 x 16B units per thread per half-tile; u32 per-lane offsets.
  // unit p = i*512+tid: row = p>>3 (0..127 in half), phys slot p&7 holds
  // logical chunk q = (p&7)^(row&7).
  unsigned aoffu[2], boffu[2];
  int ldo[2];
#pragma unroll
  for (int i = 0; i < 2; ++i) {
    const int p   = i * 512 + tid;
    const int row = p >> 3;
    const int q   = (p & 7) ^ (row & 7);
    aoffu[i] = (unsigned)(row * lda + q * 8);
    boffu[i] = (unsigned)(row * K + q * 8);
    ldo[i] = p * 8;
  }

  const int NT   = K >> 6;      // BK = 64
  const int maxH = NT * 4;

  auto stage = [&](int slot, int H) {
    const unsigned T64 = (unsigned)(H >> 2) * 64u;
    const int kind = H & 3;     // 0:A0 1:A1 2:B0 3:B1
    unsigned short* base = &sm[slot * 8192];
    if (kind & 2) {
      const unsigned add = (kind & 1) ? (unsigned)(128 * K) + T64 : T64;
      __builtin_amdgcn_global_load_lds((const AS1 void*)(Bb + boffu[0] + add),
          (AS3 void*)(base + ldo[0]), 16, 0, 0);
      __builtin_amdgcn_global_load_lds((const AS1 void*)(Bb + boffu[1] + add),
          (AS3 void*)(base + ldo[1]), 16, 0, 0);
    } else {
      const unsigned add = (kind & 1) ? (unsigned)(128 * lda) + T64 : T64;
      __builtin_amdgcn_global_load_lds((const AS1 void*)(Ab + aoffu[0] + add),
          (AS3 void*)(base + ldo[0]), 16, 0, 0);
      __builtin_amdgcn_global_load_lds((const AS1 void*)(Ab + aoffu[1] + add),
          (AS3 void*)(base + ldo[1]), 16, 0, 0);
    }
  };

  f32x4 acc[8][4] = {};
  const int laneq = lane & 15;
  const int rowe  = laneq * 64;                             // row offset (elems)
  const int sw0   = (((lane >> 4)    ) ^ (laneq & 7)) * 8;  // kk=0 chunk slot
  const int sw1   = (((lane >> 4) + 4) ^ (laneq & 7)) * 8;  // kk=1 chunk slot
  const int bhalf = (wc & 1) * 4096;                        // 64 rows into B-half

  // prologue: stage halves 0..5 (lead 6)
#pragma unroll
  for (int H = 0; H < 6; ++H)
    if (H < maxH) stage(H, H);

  int sA = wr;              // slot of my A-half for tile t
  int sB = 2 + (wc >> 1);   // slot of my B-half for tile t
  int stH = 6, stS = 6;     // staging stream position

  short8 afA[4][2], afB[4][2], bfA[2][2], bfB[2][2];

  auto stage_step = [&]() {
    if (stH < maxH) stage(stS, stH);
    ++stH; stS = (stS == 9) ? 0 : stS + 1;
  };

  // phase building blocks
  auto rdA0B0 = [&](const unsigned short* pa, const unsigned short* pb) {
#pragma unroll
    for (int j = 0; j < 4; ++j) {
      afA[j][0] = *(const short8*)(pa + j * 1024 + sw0);
      afA[j][1] = *(const short8*)(pa + j * 1024 + sw1);
    }
#pragma unroll
    for (int n = 0; n < 2; ++n) {
      bfA[n][0] = *(const short8*)(pb + n * 1024 + sw0);
      bfA[n][1] = *(const short8*)(pb + n * 1024 + sw1);
    }
  };
  auto rdB1 = [&](const unsigned short* pb) {
#pragma unroll
    for (int n = 0; n < 2; ++n) {
      bfB[n][0] = *(const short8*)(pb + (2 + n) * 1024 + sw0);
      bfB[n][1] = *(const short8*)(pb + (2 + n) * 1024 + sw1);
    }
  };
  auto rdA1 = [&](const unsigned short* pa) {
#pragma unroll
    for (int j = 0; j < 4; ++j) {
      afB[j][0] = *(const short8*)(pa + (4 + j) * 1024 + sw0);
      afB[j][1] = *(const short8*)(pa + (4 + j) * 1024 + sw1);
    }
  };
  // k OUTERMOST in every quadrant — 8 independent MFMAs between acc reuse
  auto mQ11 = [&]() {
    __builtin_amdgcn_s_setprio(1);
#pragma unroll
    for (int k = 0; k < 2; ++k)
#pragma unroll
      for (int j = 0; j < 4; ++j)
#pragma unroll
        for (int n = 0; n < 2; ++n)
          acc[4 + j][2 + n] = MFMA16(afB[j][k], bfB[n][k], acc[4 + j][2 + n]);
    __builtin_amdgcn_s_setprio(0);
  };
  auto mQ00 = [&]() {
    __builtin_amdgcn_s_setprio(1);
#pragma unroll
    for (int k = 0; k < 2; ++k)
#pragma unroll
      for (int j = 0; j < 4; ++j)
#pragma unroll
        for (int n = 0; n < 2; ++n)
          acc[j][n] = MFMA16(afA[j][k], bfA[n][k], acc[j][n]);
    __builtin_amdgcn_s_setprio(0);
  };
  auto mQ01 = [&]() {
    __builtin_amdgcn_s_setprio(1);
#pragma unroll
    for (int k = 0; k < 2; ++k)
#pragma unroll
      for (int j = 0; j < 4; ++j)
#pragma unroll
        for (int n = 0; n < 2; ++n)
          acc[j][2 + n] = MFMA16(afA[j][k], bfB[n][k], acc[j][2 + n]);
    __builtin_amdgcn_s_setprio(0);
  };
  auto mQ10 = [&]() {
    __builtin_amdgcn_s_setprio(1);
#pragma unroll
    for (int k = 0; k < 2; ++k)
#pragma unroll
      for (int j = 0; j < 4; ++j)
#pragma unroll
        for (int n = 0; n < 2; ++n)
          acc[4 + j][n] = MFMA16(afB[j][k], bfA[n][k], acc[4 + j][n]);
    __builtin_amdgcn_s_setprio(0);
  };

  for (int t = 0; t < NT; ++t) {
    // ---- K-tile boundary (the ONLY barrier) ----
    if (t + 1 < NT) asm volatile("s_waitcnt vmcnt(4)" ::: "memory");
    else            asm volatile("s_waitcnt vmcnt(0)" ::: "memory");
    __builtin_amdgcn_s_barrier();
    asm volatile("" ::: "memory");

    const unsigned short* pa = &sm[sA * 8192 + rowe];
    const unsigned short* pb = &sm[sB * 8192 + bhalf + rowe];

    if (wr == 0) {
      // parity-0: reads first, MFMA second (LDS pipe right after barrier)
      rdA0B0(pa, pb); stage_step();
      if (t) mQ11();
      rdB1(pb); stage_step();
      mQ00();
      rdA1(pa); stage_step();
      mQ01();
      stage_step();
      mQ10();
    } else {
      // parity-1: MFMA first, reads second (MFMA pipe right after barrier)
      if (t) mQ11();
      rdA0B0(pa, pb); stage_step();
      mQ00();
      rdB1(pb); stage_step();
      mQ01();
      rdA1(pa); stage_step();
      mQ10();
      stage_step();
    }

    sA += 4; if (sA >= 10) sA -= 10;
    sB += 4; if (sB >= 10) sB -= 10;
  }
  // final q11 (last tile)
  mQ11();

  // epilogue: C/D layout col=lane&15, row=(lane>>4)*4+reg
  const int rbase = bm + wr * 128 + ((lane >> 4) << 2);
  const int cbase = bn + wc * 64 + (lane & 15);
  float wv[8][4];
  if (EPI != 0) {
    const int ei = (EPI == 3) ? z : eidx;
#pragma unroll
    for (int mf = 0; mf < 8; ++mf)
#pragma unroll
      for (int r = 0; r < 4; ++r)
        wv[mf][r] = wgt[(size_t)(rbase + mf * 16 + r) * 8 + ei];
  }
#pragma unroll
  for (int mf = 0; mf < 8; ++mf) {
#pragma unroll
    for (int nf = 0; nf < 4; ++nf) {
      const int col = cbase + nf * 16;
      const float bv = bias[z * biasZ + col];
#pragma unroll
      for (int r = 0; r < 4; ++r) {
        const int row = rbase + mf * 16 + r;
        const float v = acc[mf][nf][r] + bv;
        if (EPI == 0) {
          // segmented: segment s = col>>12 is a contiguous [M,4096] buffer
          Cb[(size_t)(col >> 12) * cZ + (size_t)row * 4096 + (col & 4095)] =
              f2bf(fast_gelu(v));
        } else if (EPI == 1) {
          Cf[(size_t)row * N + col] = wv[mf][r] * v;
        } else if (EPI == 2) {
          Cf[(size_t)row * N + col] += wv[mf][r] * v;
        } else {
          Cf[z * cZ + (size_t)row * N + col] = wv[mf][r] * v;
        }
      }
    }
  }
}

// ---------- gate logits (E=8) + softmax, 1 block/token ----------
__global__ void gate_softmax(const unsigned short* __restrict__ g2,
                             const unsigned short* __restrict__ W3,
                             const float* __restrict__ b3,
                             float* __restrict__ wout, int H) {
  const int m = blockIdx.x;
  const int lane = threadIdx.x & 63;
  const int wid  = threadIdx.x >> 6;
  float acc[8] = {0.f, 0.f, 0.f, 0.f, 0.f, 0.f, 0.f, 0.f};
  const unsigned short* grow = g2 + (size_t)m * H;
  for (int k = threadIdx.x * 8; k < H; k += 256 * 8) {
    short8 gv = *(const short8*)(grow + k);
    float gf[8];
#pragma unroll
    for (int j = 0; j < 8; ++j) gf[j] = bf2f((unsigned short)gv[j]);
#pragma unroll
    for (int e = 0; e < 8; ++e) {
      short8 wvv = *(const short8*)(W3 + (size_t)e * H + k);
#pragma unroll
      for (int j = 0; j < 8; ++j) acc[e] += gf[j] * bf2f((unsigned short)wvv[j]);
    }
  }
#pragma unroll
  for (int e = 0; e < 8; ++e)
#pragma unroll
    for (int off = 32; off > 0; off >>= 1) acc[e] += __shfl_down(acc[e], off);
  __shared__ float red[4][8];
  if (lane == 0) {
#pragma unroll
    for (int e = 0; e < 8; ++e) red[wid][e] = acc[e];
  }
  __syncthreads();
  if (threadIdx.x == 0) {
    float l[8], mx = -1e30f, s = 0.f;
#pragma unroll
    for (int e = 0; e < 8; ++e) {
      l[e] = red[0][e] + red[1][e] + red[2][e] + red[3][e] + b3[e];
      mx = fmaxf(mx, l[e]);
    }
#pragma unroll
    for (int e = 0; e < 8; ++e) { l[e] = expf(l[e] - mx); s += l[e]; }
    const float inv = 1.f / s;
#pragma unroll
    for (int e = 0; e < 8; ++e) wout[(size_t)m * 8 + e] = l[e] * inv;
  }
}

// ---------- sum of 8 expert partials ----------
__global__ void reduce8(const float4* __restrict__ in, float4* __restrict__ out,
                        int n4) {
  int i = blockIdx.x * 256 + threadIdx.x;
  const int stride = gridDim.x * 256;
  for (; i < n4; i += stride) {
    float4 s = in[i];
#pragma unroll
    for (int zz = 1; zz < 8; ++zz) {
      float4 v = in[(size_t)zz * n4 + i];
      s.x += v.x; s.y += v.y; s.z += v.z; s.w += v.w;
    }
    out[i] = s;
  }
}

extern "C" void kernel_launch(void* const* d_in, const int* in_sizes, int n_in,
                              void* d_out, int out_size, void* d_ws, size_t ws_size,
                              hipStream_t stream) {
  const float* x   = (const float*)d_in[0];
  const float* gW1 = (const float*)d_in[1];
  const float* gb1 = (const float*)d_in[2];
  const float* gW2 = (const float*)d_in[3];
  const float* gb2 = (const float*)d_in[4];
  const float* gW3 = (const float*)d_in[5];
  const float* gb3 = (const float*)d_in[6];
  const float* eW1 = (const float*)d_in[7];
  const float* eb1 = (const float*)d_in[8];
  const float* eW2 = (const float*)d_in[9];
  const float* eb2 = (const float*)d_in[10];

  const int M = 4096, D = 1024, H = 4096, E = 8;
  const int NCAT = (1 + E) * H;   // 36864: [gate1 | expert1 x8] fused columns
  const size_t SEG = (size_t)M * H;   // one h segment [M,4096]

  float* outP = (float*)d_out;              // [M, D]
  float* wP   = outP + (size_t)M * D;       // [M, E]

  char* ws = (char*)d_ws;
  size_t off = 0;
  auto alloc = [&](size_t bytes) -> void* {
    void* p = ws + off;
    off += (bytes + 255) & ~(size_t)255;
    return p;
  };
  unsigned short* xb    = (unsigned short*)alloc((size_t)M * D * 2);
  unsigned short* w1cat = (unsigned short*)alloc((size_t)NCAT * D * 2);
  unsigned short* gW2b  = (unsigned short*)alloc((size_t)H * H * 2);
  unsigned short* gW3b  = (unsigned short*)alloc((size_t)E * H * 2);
  unsigned short* eW2b  = (unsigned short*)alloc((size_t)E * D * H * 2);
  unsigned short* g2b   = (unsigned short*)alloc((size_t)M * H * 2);
  float*          b1cat = (float*)alloc((size_t)NCAT * 4);
  unsigned short* h_cat = (unsigned short*)alloc((size_t)M * NCAT * 2);  // 9 segs
  const size_t base_off = off;
  const size_t eo_b = (size_t)E * M * D * 4;   // 128 MB
  const int tier1 = (ws_size >= base_off + eo_b) ? 1 : 0;

  auto cvt = [&](const float* src, unsigned short* dst, size_t n) {
    size_t n4 = n >> 2;
    size_t b = (n4 + 255) >> 8;
    if (b > 2048) b = 2048;
    cvt_f32_bf16<<<dim3((unsigned)b), dim3(256), 0, stream>>>(
        (const float4*)src, (ushort4v*)dst, n4);
  };
  cvt(x,   xb,    (size_t)M * D);
  cvt(gW1, w1cat, (size_t)H * D);
  cvt(eW1, w1cat + (size_t)H * D, (size_t)E * H * D);
  cvt(gW2, gW2b,  (size_t)H * H);
  cvt(gW3, gW3b,  (size_t)E * H);
  cvt(eW2, eW2b,  (size_t)E * D * H);
  hipMemcpyAsync(b1cat, gb1, (size_t)H * 4, hipMemcpyDeviceToDevice, stream);
  hipMemcpyAsync(b1cat + H, eb1, (size_t)E * H * 4, hipMemcpyDeviceToDevice, stream);

  // fused layer-1: h_cat[seg s] = gelu(x @ [gW1;eW1]^T + b1cat)  [M, 36864]
  gemm256<0><<<dim3(NCAT / 256, M / 256, 1), dim3(512), 0, stream>>>(
      xb, 0, D, w1cat, 0, b1cat, 0, h_cat, nullptr, SEG, nullptr, 0,
      M, NCAT, D);
  // gate2: g2 = gelu(g1 @ gW2^T + gb2)  [M,H], K=H  (A = seg0, lda=4096)
  gemm256<0><<<dim3(H / 256, M / 256, 1), dim3(512), 0, stream>>>(
      h_cat, 0, H, gW2b, 0, gb2, 0, g2b, nullptr, SEG, nullptr, 0, M, H, H);
  // softmax weights
  gate_softmax<<<dim3(M), dim3(256), 0, stream>>>(g2b, gW3b, gb3, wP, H);

  if (tier1) {
    float* eo_all = (float*)alloc(eo_b);
    // expert layer 2 grouped -> weighted partials (A = seg(1+z), lda=4096)
    gemm256<3><<<dim3(D / 256, M / 256, E), dim3(512), 0, stream>>>(
        h_cat + SEG, SEG, H, eW2b, (size_t)D * H, eb2, D,
        nullptr, eo_all, (size_t)M * D, wP, 0, M, D, H);
    reduce8<<<dim3(2048), dim3(256), 0, stream>>>(
        (const float4*)eo_all, (float4*)outP, (int)((size_t)M * D / 4));
  } else {
    for (int e = 0; e < E; ++e) {
      if (e == 0)
        gemm256<1><<<dim3(D / 256, M / 256, 1), dim3(512), 0, stream>>>(
            h_cat + (size_t)(1 + e) * SEG, 0, H, eW2b + (size_t)e * D * H, 0,
            eb2 + (size_t)e * D, 0, nullptr, outP, 0, wP, e, M, D, H);
      else
        gemm256<2><<<dim3(D / 256, M / 256, 1), dim3(512), 0, stream>>>(
            h_cat + (size_t)(1 + e) * SEG, 0, H, eW2b + (size_t)e * D * H, 0,
            eb2 + (size_t)e * D, 0, nullptr, outP, 0, wP, e, M, D, H);
    }
  }
}

// Round 12
// 1380.363 us; speedup vs baseline: 1.2157x; 1.0974x over previous
//
#include <hip/hip_runtime.h>
#include <hip/hip_bf16.h>
#include <math.h>

typedef __attribute__((ext_vector_type(8))) __bf16 bf16x8;
typedef __attribute__((ext_vector_type(8))) short short8;
typedef __attribute__((ext_vector_type(4))) float f32x4;
typedef __attribute__((ext_vector_type(4))) unsigned short ushort4v;

#define AS1 __attribute__((address_space(1)))
#define AS3 __attribute__((address_space(3)))

__device__ __forceinline__ unsigned short f2bf(float f) {
  __hip_bfloat16 h = __float2bfloat16(f);
  return __builtin_bit_cast(unsigned short, h);
}
__device__ __forceinline__ float bf2f(unsigned short s) {
  unsigned int u = ((unsigned int)s) << 16;
  return __builtin_bit_cast(float, u);
}

// fast exact-shape gelu: 0.5*v*(1+erf(v/sqrt2)), erf via A&S 7.1.26 (|err|<1.5e-7)
__device__ __forceinline__ float fast_gelu(float v) {
  const float x = v * 0.70710678118654752f;
  const float a = __builtin_fabsf(x);
  const float t = __builtin_amdgcn_rcpf(__builtin_fmaf(0.3275911f, a, 1.0f));
  float p = __builtin_fmaf(t, 1.061405429f, -1.453152027f);
  p = __builtin_fmaf(t, p, 1.421413741f);
  p = __builtin_fmaf(t, p, -0.284496736f);
  p = __builtin_fmaf(t, p, 0.254829592f);
  p = p * t;
  const float e = __builtin_amdgcn_exp2f(-a * a * 1.4426950408889634f);
  const float erfa = __builtin_fmaf(-p, e, 1.0f);
  const float erfx = __builtin_copysignf(erfa, x);
  return 0.5f * v * (1.0f + erfx);
}

// ---------- fp32 -> bf16 conversion ----------
__global__ void cvt_f32_bf16(const float4* __restrict__ in,
                             ushort4v* __restrict__ out, size_t n4) {
  size_t i = (size_t)blockIdx.x * blockDim.x + threadIdx.x;
  size_t stride = (size_t)gridDim.x * blockDim.x;
  for (; i < n4; i += stride) {
    float4 v = in[i];
    ushort4v o = { f2bf(v.x), f2bf(v.y), f2bf(v.z), f2bf(v.w) };
    out[i] = o;
  }
}

#define MFMA16(a, b, c) __builtin_amdgcn_mfma_f32_16x16x32_bf16( \
    __builtin_bit_cast(bf16x8, a), __builtin_bit_cast(bf16x8, b), c, 0, 0, 0)

// ---------- 128x128 bf16 GEMM body (m97 structure): C = A*B^T (+bias) ------
// 128x128 tile, BK=64, 4 waves (2x2), per-wave 64x64 (acc[4][4]), 32 KB
// single-buffer LDS, 2 barriers per K-tile (m97-verified 912 TF @3 blocks/CU:
// cross-block wave overlap per m114) + XOR-swizzled LDS (zero conflicts,
// r2-verified) + k-outer MFMA + setprio.
// LDS layout per operand: [128 rows][8 slots of 8 elems], chunk q of row r at
// slot q^(r&7); staged linearly (unit u -> bytes u*16), source pre-inverse-
// swizzled.
// EPI 0: Cb[(col>>12)*cZ + row*4096 + (col&4095)] = bf16(gelu(v))  (segmented)
// EPI 1: Cf[row*N+col]  = wgt[row*8+eidx] * v
// EPI 2: Cf[row*N+col] += wgt[row*8+eidx] * v
// EPI 4: Cb[row*N+col]  = bf16(v)            (unweighted partial, bf16)
template<int EPI>
__device__ __forceinline__ void gemm128_body(
    unsigned short* sA, unsigned short* sB,
    const unsigned short* __restrict__ A, int lda,
    const unsigned short* __restrict__ B, int ldb,
    const float* __restrict__ bias,
    unsigned short* __restrict__ Cb, float* __restrict__ Cf, size_t cZ,
    const float* __restrict__ wgt, int eidx,
    int bm, int bn, int N, int K) {
  const int tid  = threadIdx.x;   // 0..255
  const int lane = tid & 63;
  const int wid  = tid >> 6;      // 0..3
  const int wr   = wid >> 1;
  const int wc   = wid & 1;

  const unsigned short* Ab = A + (size_t)bm * lda;
  const unsigned short* Bb = B + (size_t)bn * ldb;

  // staging: 4 x 16B units per thread per operand (1024 units = 16 KB each)
  unsigned aoff[4], boff[4];
  int ldo[4];
#pragma unroll
  for (int i = 0; i < 4; ++i) {
    const int u    = i * 256 + tid;     // 0..1023
    const int lrow = u >> 3;            // 0..127
    const int q    = (u & 7) ^ (lrow & 7);
    aoff[i] = (unsigned)(lrow * lda + q * 8);
    boff[i] = (unsigned)(lrow * ldb + q * 8);
    ldo[i]  = u * 8;
  }

  f32x4 acc[4][4] = {};
  const int rowe  = (lane & 15) * 64;
  const int sw0   = (((lane >> 4)    ) ^ (lane & 7)) * 8;
  const int sw1   = (((lane >> 4) + 4) ^ (lane & 7)) * 8;
  const int abase = wr * 64 * 64;   // elems
  const int bbase = wc * 64 * 64;

  const int NT = K >> 6;
  unsigned kofs = 0;
  for (int t = 0; t < NT; ++t) {
    __syncthreads();   // prev tile's reads complete before overwrite
#pragma unroll
    for (int i = 0; i < 4; ++i) {
      __builtin_amdgcn_global_load_lds((const AS1 void*)(Ab + aoff[i] + kofs),
          (AS3 void*)(sA + ldo[i]), 16, 0, 0);
      __builtin_amdgcn_global_load_lds((const AS1 void*)(Bb + boff[i] + kofs),
          (AS3 void*)(sB + ldo[i]), 16, 0, 0);
    }
    kofs += 64;
    asm volatile("s_waitcnt vmcnt(0)" ::: "memory");
    __syncthreads();   // tile resident for all waves

#pragma unroll
    for (int kk = 0; kk < 2; ++kk) {
      const int sw = kk ? sw1 : sw0;
      short8 af[4], bf[4];
#pragma unroll
      for (int m = 0; m < 4; ++m)
        af[m] = *(const short8*)(sA + abase + m * 1024 + rowe + sw);
#pragma unroll
      for (int n = 0; n < 4; ++n)
        bf[n] = *(const short8*)(sB + bbase + n * 1024 + rowe + sw);
      __builtin_amdgcn_s_setprio(1);
#pragma unroll
      for (int m = 0; m < 4; ++m)
#pragma unroll
        for (int n = 0; n < 4; ++n)
          acc[m][n] = MFMA16(af[m], bf[n], acc[m][n]);
      __builtin_amdgcn_s_setprio(0);
    }
  }

  // epilogue: C/D layout col=lane&15, row=(lane>>4)*4+reg  [m89-verified]
  const int rbase = bm + wr * 64 + ((lane >> 4) << 2);
  const int cbase = bn + wc * 64 + (lane & 15);
  float wv[4][4];
  if (EPI == 1 || EPI == 2) {
#pragma unroll
    for (int m = 0; m < 4; ++m)
#pragma unroll
      for (int r = 0; r < 4; ++r)
        wv[m][r] = wgt[(size_t)(rbase + m * 16 + r) * 8 + eidx];
  }
#pragma unroll
  for (int m = 0; m < 4; ++m) {
#pragma unroll
    for (int n = 0; n < 4; ++n) {
      const int col = cbase + n * 16;
      const float bv = bias[col];
#pragma unroll
      for (int r = 0; r < 4; ++r) {
        const int row = rbase + m * 16 + r;
        const float v = acc[m][n][r] + bv;
        if (EPI == 0) {
          Cb[(size_t)(col >> 12) * cZ + (size_t)row * 4096 + (col & 4095)] =
              f2bf(fast_gelu(v));
        } else if (EPI == 1) {
          Cf[(size_t)row * N + col] = wv[m][r] * v;
        } else if (EPI == 2) {
          Cf[(size_t)row * N + col] += wv[m][r] * v;
        } else {  // EPI == 4
          Cb[(size_t)row * N + col] = f2bf(v);
        }
      }
    }
  }
}

// generic wrapper with XCD-aware swizzle (nwg % 8 == 0 for all our grids)
template<int EPI>
__global__ __launch_bounds__(256, 3)
void gemm128_k(const unsigned short* __restrict__ A, int lda,
               const unsigned short* __restrict__ B,
               const float* __restrict__ bias,
               unsigned short* __restrict__ Cb, float* __restrict__ Cf,
               size_t cZ, const float* __restrict__ wgt, int eidx,
               int N, int K) {
  __shared__ alignas(16) unsigned short sA[8192];
  __shared__ alignas(16) unsigned short sB[8192];
  const int gx  = gridDim.x;
  const int nwg = gx * gridDim.y;
  const int lin = blockIdx.y * gx + blockIdx.x;
  const int cpx = nwg >> 3;
  const int swb = (lin & 7) * cpx + (lin >> 3);
  const int bm = (swb / gx) * 128;
  const int bn = (swb % gx) * 128;
  gemm128_body<EPI>(sA, sB, A, lda, B, K, bias, Cb, Cf, cZ, wgt, eidx,
                    bm, bn, N, K);
}

// merged gate2 + unweighted expert2 (concurrent in one launch, 3072 blocks):
//   blocks [0,1024):    gate2  g2 = gelu(h0 @ gW2^T + gb2)      [M,4096]
//   blocks [1024,3072): expert eo[e] = bf16(h_{1+e} @ eW2[e]^T + eb2[e]) [M,1024]
__global__ __launch_bounds__(256, 3)
void merged_g2e2(const unsigned short* __restrict__ h_cat, size_t SEG,
                 const unsigned short* __restrict__ gW2b,
                 const float* __restrict__ gb2,
                 unsigned short* __restrict__ g2b,
                 const unsigned short* __restrict__ eW2b,
                 const float* __restrict__ eb2,
                 unsigned short* __restrict__ eo_bf, size_t eoZ,
                 int D, int H) {
  __shared__ alignas(16) unsigned short sA[8192];
  __shared__ alignas(16) unsigned short sB[8192];
  const int bid = blockIdx.x;
  if (bid < 1024) {
    const int swb = (bid & 7) * 128 + (bid >> 3);   // bijective on [0,1024)
    const int bx = swb & 31, by = swb >> 5;         // 32 x 32
    gemm128_body<0>(sA, sB, h_cat, H, gW2b, H, gb2, g2b, nullptr,
                    0, nullptr, 0, by * 128, bx * 128, H, H);
  } else {
    const int eb  = bid - 1024;
    const int e   = eb >> 8;                        // 0..7
    const int sub = eb & 255;
    const int swb = (sub & 7) * 32 + (sub >> 3);    // bijective on [0,256)
    const int bx = swb & 7, by = swb >> 3;          // 8 x 32
    gemm128_body<4>(sA, sB, h_cat + (size_t)(1 + e) * SEG, H,
                    eW2b + (size_t)e * D * H, H, eb2 + (size_t)e * D,
                    eo_bf + (size_t)e * eoZ, nullptr, 0, nullptr, 0,
                    by * 128, bx * 128, D, H);
  }
}

// ---------- gate logits (E=8) + softmax, 1 block/token ----------
__global__ void gate_softmax(const unsigned short* __restrict__ g2,
                             const unsigned short* __restrict__ W3,
                             const float* __restrict__ b3,
                             float* __restrict__ wout, int H) {
  const int m = blockIdx.x;
  const int lane = threadIdx.x & 63;
  const int wid  = threadIdx.x >> 6;
  float acc[8] = {0.f, 0.f, 0.f, 0.f, 0.f, 0.f, 0.f, 0.f};
  const unsigned short* grow = g2 + (size_t)m * H;
  for (int k = threadIdx.x * 8; k < H; k += 256 * 8) {
    short8 gv = *(const short8*)(grow + k);
    float gf[8];
#pragma unroll
    for (int j = 0; j < 8; ++j) gf[j] = bf2f((unsigned short)gv[j]);
#pragma unroll
    for (int e = 0; e < 8; ++e) {
      short8 wvv = *(const short8*)(W3 + (size_t)e * H + k);
#pragma unroll
      for (int j = 0; j < 8; ++j) acc[e] += gf[j] * bf2f((unsigned short)wvv[j]);
    }
  }
#pragma unroll
  for (int e = 0; e < 8; ++e)
#pragma unroll
    for (int off = 32; off > 0; off >>= 1) acc[e] += __shfl_down(acc[e], off);
  __shared__ float red[4][8];
  if (lane == 0) {
#pragma unroll
    for (int e = 0; e < 8; ++e) red[wid][e] = acc[e];
  }
  __syncthreads();
  if (threadIdx.x == 0) {
    float l[8], mx = -1e30f, s = 0.f;
#pragma unroll
    for (int e = 0; e < 8; ++e) {
      l[e] = red[0][e] + red[1][e] + red[2][e] + red[3][e] + b3[e];
      mx = fmaxf(mx, l[e]);
    }
#pragma unroll
    for (int e = 0; e < 8; ++e) { l[e] = expf(l[e] - mx); s += l[e]; }
    const float inv = 1.f / s;
#pragma unroll
    for (int e = 0; e < 8; ++e) wout[(size_t)m * 8 + e] = l[e] * inv;
  }
}

// ---------- weighted sum of 8 bf16 expert partials ----------
__global__ void reduce8w(const unsigned short* __restrict__ eo,
                         const float* __restrict__ w,
                         float* __restrict__ out, int n8, int D) {
  int i = blockIdx.x * 256 + threadIdx.x;   // unit = 8 contiguous outputs
  const int stride = gridDim.x * 256;
  for (; i < n8; i += stride) {
    const int m = (i * 8) / D;
    const float* wm = w + (size_t)m * 8;
    float s[8] = {0.f, 0.f, 0.f, 0.f, 0.f, 0.f, 0.f, 0.f};
#pragma unroll
    for (int e = 0; e < 8; ++e) {
      const short8 v = *(const short8*)(eo + (size_t)e * n8 * 8 + (size_t)i * 8);
      const float we = wm[e];
#pragma unroll
      for (int j = 0; j < 8; ++j) s[j] += we * bf2f((unsigned short)v[j]);
    }
    float4* o = (float4*)(out + (size_t)i * 8);
    o[0] = make_float4(s[0], s[1], s[2], s[3]);
    o[1] = make_float4(s[4], s[5], s[6], s[7]);
  }
}

extern "C" void kernel_launch(void* const* d_in, const int* in_sizes, int n_in,
                              void* d_out, int out_size, void* d_ws, size_t ws_size,
                              hipStream_t stream) {
  const float* x   = (const float*)d_in[0];
  const float* gW1 = (const float*)d_in[1];
  const float* gb1 = (const float*)d_in[2];
  const float* gW2 = (const float*)d_in[3];
  const float* gb2 = (const float*)d_in[4];
  const float* gW3 = (const float*)d_in[5];
  const float* gb3 = (const float*)d_in[6];
  const float* eW1 = (const float*)d_in[7];
  const float* eb1 = (const float*)d_in[8];
  const float* eW2 = (const float*)d_in[9];
  const float* eb2 = (const float*)d_in[10];

  const int M = 4096, D = 1024, H = 4096, E = 8;
  const int NCAT = (1 + E) * H;       // 36864
  const size_t SEG = (size_t)M * H;   // one h segment [M,4096]

  float* outP = (float*)d_out;              // [M, D]
  float* wP   = outP + (size_t)M * D;       // [M, E]

  char* ws = (char*)d_ws;
  size_t off = 0;
  auto alloc = [&](size_t bytes) -> void* {
    void* p = ws + off;
    off += (bytes + 255) & ~(size_t)255;
    return p;
  };
  unsigned short* xb    = (unsigned short*)alloc((size_t)M * D * 2);
  unsigned short* w1cat = (unsigned short*)alloc((size_t)NCAT * D * 2);
  unsigned short* gW2b  = (unsigned short*)alloc((size_t)H * H * 2);
  unsigned short* gW3b  = (unsigned short*)alloc((size_t)E * H * 2);
  unsigned short* eW2b  = (unsigned short*)alloc((size_t)E * D * H * 2);
  unsigned short* g2b   = (unsigned short*)alloc((size_t)M * H * 2);
  float*          b1cat = (float*)alloc((size_t)NCAT * 4);
  unsigned short* h_cat = (unsigned short*)alloc((size_t)M * NCAT * 2);  // 9 segs
  const size_t base_off = off;
  const size_t eo_b = (size_t)E * M * D * 2;   // bf16 partials, 64 MB
  const int tier1 = (ws_size >= base_off + eo_b) ? 1 : 0;

  auto cvt = [&](const float* src, unsigned short* dst, size_t n) {
    size_t n4 = n >> 2;
    size_t b = (n4 + 255) >> 8;
    if (b > 2048) b = 2048;
    cvt_f32_bf16<<<dim3((unsigned)b), dim3(256), 0, stream>>>(
        (const float4*)src, (ushort4v*)dst, n4);
  };
  cvt(x,   xb,    (size_t)M * D);
  cvt(gW1, w1cat, (size_t)H * D);
  cvt(eW1, w1cat + (size_t)H * D, (size_t)E * H * D);
  cvt(gW2, gW2b,  (size_t)H * H);
  cvt(gW3, gW3b,  (size_t)E * H);
  cvt(eW2, eW2b,  (size_t)E * D * H);
  hipMemcpyAsync(b1cat, gb1, (size_t)H * 4, hipMemcpyDeviceToDevice, stream);
  hipMemcpyAsync(b1cat + H, eb1, (size_t)E * H * 4, hipMemcpyDeviceToDevice, stream);

  // fused layer-1: h_cat[seg s] = gelu(x @ [gW1;eW1]^T + b1cat)  [M, 36864]
  gemm128_k<0><<<dim3(NCAT / 128, M / 128), dim3(256), 0, stream>>>(
      xb, D, w1cat, b1cat, h_cat, nullptr, SEG, nullptr, 0, NCAT, D);

  if (tier1) {
    unsigned short* eo_bf = (unsigned short*)alloc(eo_b);
    // gate2 and unweighted expert2 concurrently (one 3072-block launch)
    merged_g2e2<<<dim3(3072), dim3(256), 0, stream>>>(
        h_cat, SEG, gW2b, gb2, g2b, eW2b, eb2, eo_bf, (size_t)M * D, D, H);
    // softmax weights
    gate_softmax<<<dim3(M), dim3(256), 0, stream>>>(g2b, gW3b, gb3, wP, H);
    // out = sum_e w[:,e] * eo[e]
    reduce8w<<<dim3(2048), dim3(256), 0, stream>>>(
        eo_bf, wP, outP, (int)((size_t)M * D / 8), D);
  } else {
    // fallback: gate2, softmax, then sequential weighted experts
    gemm128_k<0><<<dim3(H / 128, M / 128), dim3(256), 0, stream>>>(
        h_cat, H, gW2b, gb2, g2b, nullptr, SEG, nullptr, 0, H, H);
    gate_softmax<<<dim3(M), dim3(256), 0, stream>>>(g2b, gW3b, gb3, wP, H);
    for (int e = 0; e < E; ++e) {
      if (e == 0)
        gemm128_k<1><<<dim3(D / 128, M / 128), dim3(256), 0, stream>>>(
            h_cat + (size_t)(1 + e) * SEG, H, eW2b + (size_t)e * D * H,
            eb2 + (size_t)e * D, nullptr, outP, 0, wP, e, D, H);
      else
        gemm128_k<2><<<dim3(D / 128, M / 128), dim3(256), 0, stream>>>(
            h_cat + (size_t)(1 + e) * SEG, H, eW2b + (size_t)e * D * H,
            eb2 + (size_t)e * D, nullptr, outP, 0, wP, e, D, H);
    }
  }
}